// Round 2
// baseline (1008.278 us; speedup 1.0000x reference)
//
#include <hip/hip_runtime.h>
#include <cstdint>

#define N 4096
#define D 1024
#define BM 128
#define BN 128
#define BK 16
#define NSTEPS (D / BK)

// Monotone map fp32 -> u32 so unsigned compare == float compare (ascending).
__device__ __forceinline__ unsigned int orderable(float f) {
    unsigned int b = __float_as_uint(f);
    return (b & 0x80000000u) ? ~b : (b | 0x80000000u);
}

__global__ void init_keys(unsigned long long* keys) {
    int t = blockIdx.x * blockDim.x + threadIdx.x;
    if (t < 2 * N) keys[t] = 0xFFFFFFFFFFFFFFFFull;
}

// Fused X @ X^T tile + masked row-argmin epilogue.
// keys_ap[i] / keys_an[i] = (orderable(minval) << 32) | argmin_col, via atomicMin.
__global__ __launch_bounds__(256) void gemm_argmin(
    const float* __restrict__ A, const int* __restrict__ labels,
    unsigned long long* __restrict__ keys_ap,
    unsigned long long* __restrict__ keys_an)
{
    __shared__ float As[BK][BM];
    __shared__ float Bs[BK][BN];
    __shared__ int labM[BM];
    __shared__ int labN[BN];

    const int tid = threadIdx.x;
    const int tx = tid & 15;        // column group (8 cols)
    const int ty = tid >> 4;        // row group (8 rows)
    const int rowBase = blockIdx.y * BM;
    const int colBase = blockIdx.x * BN;

    if (tid < BM) labM[tid] = labels[rowBase + tid];
    else          labN[tid - BM] = labels[colBase + (tid - BM)];

    // Global->LDS staging assignment: 512 float4 slots per tile, 2 per thread.
    const int q0 = tid, q1 = tid + 256;
    const int ar0 = q0 >> 2, ak0 = (q0 & 3) << 2;
    const int ar1 = q1 >> 2, ak1 = (q1 & 3) << 2;

    const float* pA0 = A + (size_t)(rowBase + ar0) * D + ak0;
    const float* pA1 = A + (size_t)(rowBase + ar1) * D + ak1;
    const float* pB0 = A + (size_t)(colBase + ar0) * D + ak0;
    const float* pB1 = A + (size_t)(colBase + ar1) * D + ak1;

    float acc[8][8];
#pragma unroll
    for (int i = 0; i < 8; ++i)
#pragma unroll
        for (int j = 0; j < 8; ++j) acc[i][j] = 0.0f;

    // Prologue: load tile 0
    float4 pa0 = *(const float4*)(pA0);
    float4 pa1 = *(const float4*)(pA1);
    float4 pb0 = *(const float4*)(pB0);
    float4 pb1 = *(const float4*)(pB1);

    As[ak0 + 0][ar0] = pa0.x; As[ak0 + 1][ar0] = pa0.y;
    As[ak0 + 2][ar0] = pa0.z; As[ak0 + 3][ar0] = pa0.w;
    As[ak1 + 0][ar1] = pa1.x; As[ak1 + 1][ar1] = pa1.y;
    As[ak1 + 2][ar1] = pa1.z; As[ak1 + 3][ar1] = pa1.w;
    Bs[ak0 + 0][ar0] = pb0.x; Bs[ak0 + 1][ar0] = pb0.y;
    Bs[ak0 + 2][ar0] = pb0.z; Bs[ak0 + 3][ar0] = pb0.w;
    Bs[ak1 + 0][ar1] = pb1.x; Bs[ak1 + 1][ar1] = pb1.y;
    Bs[ak1 + 2][ar1] = pb1.z; Bs[ak1 + 3][ar1] = pb1.w;
    __syncthreads();

    for (int step = 0; step < NSTEPS; ++step) {
        const bool has_next = (step + 1) < NSTEPS;
        if (has_next) {
            const int off = (step + 1) * BK;
            pa0 = *(const float4*)(pA0 + off);
            pa1 = *(const float4*)(pA1 + off);
            pb0 = *(const float4*)(pB0 + off);
            pb1 = *(const float4*)(pB1 + off);
        }

#pragma unroll
        for (int k = 0; k < BK; ++k) {
            float4 a0 = *(const float4*)(&As[k][ty * 8]);
            float4 a1 = *(const float4*)(&As[k][ty * 8 + 4]);
            float4 b0 = *(const float4*)(&Bs[k][tx * 8]);
            float4 b1 = *(const float4*)(&Bs[k][tx * 8 + 4]);
            float a[8] = {a0.x, a0.y, a0.z, a0.w, a1.x, a1.y, a1.z, a1.w};
            float b[8] = {b0.x, b0.y, b0.z, b0.w, b1.x, b1.y, b1.z, b1.w};
#pragma unroll
            for (int mi = 0; mi < 8; ++mi)
#pragma unroll
                for (int ni = 0; ni < 8; ++ni)
                    acc[mi][ni] = fmaf(a[mi], b[ni], acc[mi][ni]);
        }

        if (has_next) {
            __syncthreads();
            As[ak0 + 0][ar0] = pa0.x; As[ak0 + 1][ar0] = pa0.y;
            As[ak0 + 2][ar0] = pa0.z; As[ak0 + 3][ar0] = pa0.w;
            As[ak1 + 0][ar1] = pa1.x; As[ak1 + 1][ar1] = pa1.y;
            As[ak1 + 2][ar1] = pa1.z; As[ak1 + 3][ar1] = pa1.w;
            Bs[ak0 + 0][ar0] = pb0.x; Bs[ak0 + 1][ar0] = pb0.y;
            Bs[ak0 + 2][ar0] = pb0.z; Bs[ak0 + 3][ar0] = pb0.w;
            Bs[ak1 + 0][ar1] = pb1.x; Bs[ak1 + 1][ar1] = pb1.y;
            Bs[ak1 + 2][ar1] = pb1.z; Bs[ak1 + 3][ar1] = pb1.w;
            __syncthreads();
        }
    }

    // Epilogue: masked argmin over this block's 128 columns, per row.
#pragma unroll
    for (int mi = 0; mi < 8; ++mi) {
        const int i = rowBase + ty * 8 + mi;
        const int li = labM[ty * 8 + mi];
        float bestAp = __builtin_huge_valf(); int bestApJ = 0;
        float bestAn = __builtin_huge_valf(); int bestAnJ = 0;
#pragma unroll
        for (int ni = 0; ni < 8; ++ni) {
            const int j = colBase + tx * 8 + ni;
            const int lj = labN[tx * 8 + ni];
            const float v = acc[mi][ni];
            const bool same_lab = (li == lj);
            const float vap = (same_lab && (i != j)) ? v : v + 2.0f;
            const float van = (!same_lab) ? v : v + 2.0f;
            if (vap < bestAp) { bestAp = vap; bestApJ = j; }
            if (van < bestAn) { bestAn = van; bestAnJ = j; }
        }
        unsigned long long kap =
            ((unsigned long long)orderable(bestAp) << 32) | (unsigned)bestApJ;
        unsigned long long kan =
            ((unsigned long long)orderable(bestAn) << 32) | (unsigned)bestAnJ;
        // Reduce across the 16 lanes (same ty) that share these rows.
#pragma unroll
        for (int off = 1; off < 16; off <<= 1) {
            unsigned long long o1 = __shfl_xor(kap, off);
            kap = (o1 < kap) ? o1 : kap;
            unsigned long long o2 = __shfl_xor(kan, off);
            kan = (o2 < kan) ? o2 : kan;
        }
        if (tx == 0) {
            atomicMin(&keys_ap[i], kap);
            atomicMin(&keys_an[i], kan);
        }
    }
}

__global__ void gather_rows(const float* __restrict__ A,
                            const unsigned long long* __restrict__ keys_ap,
                            const unsigned long long* __restrict__ keys_an,
                            float* __restrict__ out)
{
    const int row = blockIdx.x;
    const int t = threadIdx.x;
    const int ja = (int)(keys_ap[row] & 0xFFFFFFFFull);
    const int jn = (int)(keys_an[row] & 0xFFFFFFFFull);
    const float4* Av = (const float4*)A;
    float4* Ov = (float4*)out;
    Ov[(size_t)row * (D / 4) + t]       = Av[(size_t)ja * (D / 4) + t];
    Ov[(size_t)(N + row) * (D / 4) + t] = Av[(size_t)jn * (D / 4) + t];
}

extern "C" void kernel_launch(void* const* d_in, const int* in_sizes, int n_in,
                              void* d_out, int out_size, void* d_ws, size_t ws_size,
                              hipStream_t stream) {
    const float* A = (const float*)d_in[0];
    const int* labels = (const int*)d_in[1];  // harness delivers integer inputs as int32
    float* out = (float*)d_out;
    unsigned long long* keys = (unsigned long long*)d_ws;  // 2*N*8 = 64 KB

    init_keys<<<(2 * N + 255) / 256, 256, 0, stream>>>(keys);
    dim3 grid(N / BN, N / BM);
    gemm_argmin<<<grid, 256, 0, stream>>>(A, labels, keys, keys + N);
    gather_rows<<<N, 256, 0, stream>>>(A, keys, keys + N, out);
}

// Round 3
// 186.827 us; speedup vs baseline: 5.3969x; 5.3969x over previous
//
#include <hip/hip_runtime.h>
#include <cstdint>

#define N 4096
#define D 1024
#define KC_COUNT (D / 32)   // 32 k-chunks of 32

typedef _Float16 f16;
typedef __attribute__((ext_vector_type(8))) _Float16 f16x8;
typedef __attribute__((ext_vector_type(4))) float f32x4;

// Monotone map fp32 -> u32 so unsigned compare == float compare (ascending).
__device__ __forceinline__ unsigned int orderable(float f) {
    unsigned int b = __float_as_uint(f);
    return (b & 0x80000000u) ? ~b : (b | 0x80000000u);
}

__device__ __forceinline__ void async_copy16(const f16* g, f16* l) {
    __builtin_amdgcn_global_load_lds(
        (const __attribute__((address_space(1))) uint32_t*)(const void*)g,
        (__attribute__((address_space(3))) uint32_t*)(void*)l,
        16 /*bytes*/, 0 /*offset*/, 0 /*aux*/);
}

__global__ void init_keys(unsigned long long* keys) {
    int t = blockIdx.x * blockDim.x + threadIdx.x;
    if (t < 2 * N) keys[t] = 0xFFFFFFFFFFFFFFFFull;
}

// Split fp32 X into f16 hi/lo planes, pre-swizzled into MFMA fragment lane
// order: Xsw[((rg*KC + kc)*2 + hl)*512 + lane*8 .. +8], where rg=row>>4,
// kc=k>>5, lane=((k>>3)&3)<<4 | (row&15). One thread per 8-elem chunk.
__global__ __launch_bounds__(256) void split_swizzle(
    const float* __restrict__ X, f16* __restrict__ Xsw)
{
    int t = blockIdx.x * 256 + threadIdx.x;   // 0 .. N*D/8-1
    int row = t >> 7;                          // D/8 = 128 chunks per row
    int c8 = t & 127;
    const float4* p = (const float4*)(X + (size_t)row * D + c8 * 8);
    float4 x0 = p[0], x1 = p[1];
    float xs[8] = {x0.x, x0.y, x0.z, x0.w, x1.x, x1.y, x1.z, x1.w};
    union { f16 h[8]; uint4 u; } hi, lo;
#pragma unroll
    for (int i = 0; i < 8; ++i) {
        f16 h = (f16)xs[i];
        hi.h[i] = h;
        lo.h[i] = (f16)(xs[i] - (float)h);
    }
    int rg = row >> 4, m = row & 15, kc = c8 >> 2, q = c8 & 3;
    int lane = (q << 4) | m;
    size_t base = (((size_t)rg * KC_COUNT + kc) * 2) * 512 + lane * 8;
    *(uint4*)(Xsw + base) = hi.u;          // hl=0
    *(uint4*)(Xsw + base + 512) = lo.u;    // hl=1
}

// 128x128 tile of dist = X @ X^T via f16x2-split MFMA (hi*hi + hi*lo + lo*hi),
// fused masked row-argmin epilogue -> atomicMin keys.
__global__ __launch_bounds__(256) void gemm_argmin_mfma(
    const f16* __restrict__ Xsw, const int* __restrict__ labels,
    unsigned long long* __restrict__ keys_ap,
    unsigned long long* __restrict__ keys_an)
{
    __shared__ f16 As[8 * 2 * 512];   // [rgLocal(8)][hl(2)][lane(64)][8]
    __shared__ f16 Bs[8 * 2 * 512];
    __shared__ int labM[128], labN[128];

    const int tid = threadIdx.x;
    const int lane = tid & 63;
    const int w = tid >> 6;           // wave 0..3
    const int wr = w >> 1, wc = w & 1; // 2x2 wave grid, 64x64 region each
    const int bi = blockIdx.y, bj = blockIdx.x;
    const int rowBase = bi * 128, colBase = bj * 128;

    if (tid < 128) labM[tid] = labels[rowBase + tid];
    else           labN[tid - 128] = labels[colBase + tid - 128];

    f32x4 acc[4][4];
#pragma unroll
    for (int mi = 0; mi < 4; ++mi)
#pragma unroll
        for (int ni = 0; ni < 4; ++ni) acc[mi][ni] = (f32x4){0.f, 0.f, 0.f, 0.f};

    // Wave w stages loads L = w*8 .. w*8+7 (32 total: A/B x 8rg x hi/lo)
    const f16* g[8];
    f16* lp[8];
#pragma unroll
    for (int j = 0; j < 8; ++j) {
        int L = w * 8 + j;
        int isB = L >> 4, rem = L & 15, rgL = rem >> 1, hl = rem & 1;
        int rgG = (isB ? bj : bi) * 8 + rgL;
        g[j] = Xsw + ((((size_t)rgG * KC_COUNT) * 2 + hl) * 64 + lane) * 8;  // kc=0
        lp[j] = (isB ? Bs : As) + (rgL * 2 + hl) * 512;  // wave-uniform base
    }

    for (int kc = 0; kc < KC_COUNT; ++kc) {
#pragma unroll
        for (int j = 0; j < 8; ++j)
            async_copy16(g[j] + (size_t)kc * 1024, lp[j]);
        __syncthreads();   // drains vmcnt(0): LDS tile complete

        f16x8 ah[4], al[4], bh[4], bl[4];
#pragma unroll
        for (int t2 = 0; t2 < 4; ++t2) {
            int rgA = wr * 4 + t2, rgB = wc * 4 + t2;
            ah[t2] = *(const f16x8*)(As + (rgA * 2 + 0) * 512 + lane * 8);
            al[t2] = *(const f16x8*)(As + (rgA * 2 + 1) * 512 + lane * 8);
            bh[t2] = *(const f16x8*)(Bs + (rgB * 2 + 0) * 512 + lane * 8);
            bl[t2] = *(const f16x8*)(Bs + (rgB * 2 + 1) * 512 + lane * 8);
        }
#pragma unroll
        for (int mi = 0; mi < 4; ++mi)
#pragma unroll
            for (int ni = 0; ni < 4; ++ni) {
                acc[mi][ni] = __builtin_amdgcn_mfma_f32_16x16x32_f16(
                    ah[mi], bh[ni], acc[mi][ni], 0, 0, 0);
                acc[mi][ni] = __builtin_amdgcn_mfma_f32_16x16x32_f16(
                    ah[mi], bl[ni], acc[mi][ni], 0, 0, 0);
                acc[mi][ni] = __builtin_amdgcn_mfma_f32_16x16x32_f16(
                    al[mi], bh[ni], acc[mi][ni], 0, 0, 0);
            }
        __syncthreads();   // all reads done before next stage overwrites
    }

    // Epilogue. C/D layout (16x16): col = lane&15, row = (lane>>4)*4 + reg.
    const int g16 = lane >> 4, c16 = lane & 15;
#pragma unroll
    for (int mi = 0; mi < 4; ++mi) {
#pragma unroll
        for (int reg = 0; reg < 4; ++reg) {
            const int rloc = wr * 64 + mi * 16 + g16 * 4 + reg;
            const int i = rowBase + rloc;
            const int li = labM[rloc];
            float bestAp = __builtin_huge_valf(); int jAp = 0;
            float bestAn = __builtin_huge_valf(); int jAn = 0;
#pragma unroll
            for (int ni = 0; ni < 4; ++ni) {
                const int cloc = wc * 64 + ni * 16 + c16;
                const int jcol = colBase + cloc;
                const int lj = labN[cloc];
                const float v = acc[mi][ni][reg];
                const bool same = (li == lj);
                const float vap = (same && (i != jcol)) ? v : v + 2.0f;
                const float van = (!same) ? v : v + 2.0f;
                if (vap < bestAp) { bestAp = vap; jAp = jcol; }
                if (van < bestAn) { bestAn = van; jAn = jcol; }
            }
            unsigned long long kap =
                ((unsigned long long)orderable(bestAp) << 32) | (unsigned)jAp;
            unsigned long long kan =
                ((unsigned long long)orderable(bestAn) << 32) | (unsigned)jAn;
#pragma unroll
            for (int off = 1; off < 16; off <<= 1) {
                unsigned long long o = __shfl_xor(kap, off); kap = o < kap ? o : kap;
                o = __shfl_xor(kan, off); kan = o < kan ? o : kan;
            }
            if (c16 == 0) {
                atomicMin(&keys_ap[i], kap);
                atomicMin(&keys_an[i], kan);
            }
        }
    }
}

__global__ void gather_rows(const float* __restrict__ A,
                            const unsigned long long* __restrict__ keys_ap,
                            const unsigned long long* __restrict__ keys_an,
                            float* __restrict__ out)
{
    const int row = blockIdx.x;
    const int t = threadIdx.x;
    const int ja = (int)(keys_ap[row] & 0xFFFFFFFFull);
    const int jn = (int)(keys_an[row] & 0xFFFFFFFFull);
    const float4* Av = (const float4*)A;
    float4* Ov = (float4*)out;
    Ov[(size_t)row * (D / 4) + t]       = Av[(size_t)ja * (D / 4) + t];
    Ov[(size_t)(N + row) * (D / 4) + t] = Av[(size_t)jn * (D / 4) + t];
}

extern "C" void kernel_launch(void* const* d_in, const int* in_sizes, int n_in,
                              void* d_out, int out_size, void* d_ws, size_t ws_size,
                              hipStream_t stream) {
    const float* A = (const float*)d_in[0];
    const int* labels = (const int*)d_in[1];  // integer inputs arrive as int32
    float* out = (float*)d_out;

    unsigned long long* keys = (unsigned long long*)d_ws;          // 64 KB
    f16* Xsw = (f16*)((char*)d_ws + 65536);                        // 16 MB hi+lo

    init_keys<<<32, 256, 0, stream>>>(keys);
    split_swizzle<<<(N * D / 8) / 256, 256, 0, stream>>>(A, Xsw);
    gemm_argmin_mfma<<<dim3(N / 128, N / 128), 256, 0, stream>>>(
        Xsw, labels, keys, keys + N);
    gather_rows<<<N, 256, 0, stream>>>(A, keys, keys + N, out);
}

// Round 4
// 176.017 us; speedup vs baseline: 5.7283x; 1.0614x over previous
//
#include <hip/hip_runtime.h>
#include <cstdint>

#define N 4096
#define D 1024
#define KC_COUNT (D / 32)   // 32 k-chunks of 32
#define TB (N / 128)        // 32 tile-blocks per dim
#define NBLK (TB * (TB + 1) / 2)   // 528 upper-triangular block pairs

typedef _Float16 f16;
typedef __attribute__((ext_vector_type(4))) _Float16 f16x4;
typedef __attribute__((ext_vector_type(8))) _Float16 f16x8;
typedef __attribute__((ext_vector_type(4))) float f32x4;

// Monotone map fp32 -> u32 so unsigned compare == float compare (ascending).
__device__ __forceinline__ unsigned int orderable(float f) {
    unsigned int b = __float_as_uint(f);
    return (b & 0x80000000u) ? ~b : (b | 0x80000000u);
}

__device__ __forceinline__ void async_copy16(const f16* g, f16* l) {
    __builtin_amdgcn_global_load_lds(
        (const __attribute__((address_space(1))) uint32_t*)(const void*)g,
        (__attribute__((address_space(3))) uint32_t*)(void*)l,
        16 /*bytes*/, 0 /*offset*/, 0 /*aux*/);
}

// Split fp32 X into f16 hi/lo planes pre-swizzled into MFMA fragment order:
// chunk (rg, kc, hl) holds 512 f16 ordered by lane = (q<<4)|m, elem = k&7,
// where row = rg*16+m, k = kc*32+q*8+elem.
// Coalesced read -> LDS row-major (conflict-free) -> coalesced swizzled store.
// Also initializes the 2*N argmin keys (fused former init_keys).
#define ROW_PAD 8
#define ROW_STRIDE (D + ROW_PAD)
__global__ __launch_bounds__(256) void split_swizzle(
    const float* __restrict__ X, f16* __restrict__ Xsw,
    unsigned long long* __restrict__ keys)
{
    __shared__ f16 Hs[16 * ROW_STRIDE];
    __shared__ f16 Ls[16 * ROW_STRIDE];
    const int tid = threadIdx.x;
    const int rg = blockIdx.x;                 // 0..255, 16 rows each
    if (tid < 32) keys[rg * 32 + tid] = 0xFFFFFFFFFFFFFFFFull;

    const float4* src = (const float4*)(X + (size_t)rg * 16 * D);
#pragma unroll
    for (int it = 0; it < 16; ++it) {
        const int idx4 = it * 256 + tid;       // 0..4095 float4 slots
        const int row = idx4 >> 8;
        const int k4 = (idx4 & 255) * 4;
        const float4 v = src[idx4];
        const float xs[4] = {v.x, v.y, v.z, v.w};
        f16x4 h, l;
#pragma unroll
        for (int i = 0; i < 4; ++i) {
            f16 hh = (f16)xs[i];
            h[i] = hh;
            l[i] = (f16)(xs[i] - (float)hh);
        }
        *(f16x4*)(Hs + row * ROW_STRIDE + k4) = h;
        *(f16x4*)(Ls + row * ROW_STRIDE + k4) = l;
    }
    __syncthreads();
#pragma unroll
    for (int hl = 0; hl < 2; ++hl) {
        const f16* lds = hl ? Ls : Hs;
#pragma unroll
        for (int it = 0; it < 8; ++it) {
            const int o = it * 256 + tid;      // uint4 slot among 2048
            const int kc = o >> 6, lo_ = o & 63;
            const int q = lo_ >> 4, m = lo_ & 15;
            const uint4 v = *(const uint4*)(lds + m * ROW_STRIDE + kc * 32 + q * 8);
            *(uint4*)(Xsw + (((size_t)rg * KC_COUNT + kc) * 2 + hl) * 512 + lo_ * 8) = v;
        }
    }
}

// Upper-triangular 128x128 tile of dist = X @ X^T via f16-split MFMA
// (hi*hi + hi*lo + lo*hi), fused masked argmin for BOTH the tile's rows
// (over its cols) and, off-diagonal, its cols (over its rows, transposed).
__global__ __launch_bounds__(256) void gemm_argmin_sym(
    const f16* __restrict__ Xsw, const int* __restrict__ labels,
    unsigned long long* __restrict__ keys_ap,
    unsigned long long* __restrict__ keys_an)
{
    __shared__ f16 As[8 * 2 * 512];   // [rgLocal(8)][hl(2)][lane(64)][8]
    __shared__ f16 Bs[8 * 2 * 512];
    __shared__ int labM[128], labN[128];

    // Decode linear block id -> (bi, bj) with bi <= bj.
    int r = blockIdx.x, bi = 0;
    while (r >= TB - bi) { r -= TB - bi; ++bi; }
    const int bj = bi + r;

    const int tid = threadIdx.x;
    const int lane = tid & 63;
    const int w = tid >> 6;            // wave 0..3
    const int wr = w >> 1, wc = w & 1; // 2x2 wave grid, 64x64 region each
    const int rowBase = bi * 128, colBase = bj * 128;

    if (tid < 128) labM[tid] = labels[rowBase + tid];
    else           labN[tid - 128] = labels[colBase + tid - 128];

    f32x4 acc[4][4];
#pragma unroll
    for (int mi = 0; mi < 4; ++mi)
#pragma unroll
        for (int ni = 0; ni < 4; ++ni) acc[mi][ni] = (f32x4){0.f, 0.f, 0.f, 0.f};

    // Wave w stages loads L = w*8 .. w*8+7 (32 total: A/B x 8rg x hi/lo)
    const f16* g[8];
    f16* lp[8];
#pragma unroll
    for (int j = 0; j < 8; ++j) {
        int L = w * 8 + j;
        int isB = L >> 4, rem = L & 15, rgL = rem >> 1, hl = rem & 1;
        int rgG = (isB ? bj : bi) * 8 + rgL;
        g[j] = Xsw + ((((size_t)rgG * KC_COUNT) * 2 + hl) * 64 + lane) * 8;  // kc=0
        lp[j] = (isB ? Bs : As) + (rgL * 2 + hl) * 512;  // wave-uniform base
    }

    for (int kc = 0; kc < KC_COUNT; ++kc) {
#pragma unroll
        for (int j = 0; j < 8; ++j)
            async_copy16(g[j] + (size_t)kc * 1024, lp[j]);
        __syncthreads();   // drains vmcnt(0): LDS tile complete

        f16x8 ah[4], al[4], bh[4], bl[4];
#pragma unroll
        for (int t2 = 0; t2 < 4; ++t2) {
            int rgA = wr * 4 + t2, rgB = wc * 4 + t2;
            ah[t2] = *(const f16x8*)(As + (rgA * 2 + 0) * 512 + lane * 8);
            al[t2] = *(const f16x8*)(As + (rgA * 2 + 1) * 512 + lane * 8);
            bh[t2] = *(const f16x8*)(Bs + (rgB * 2 + 0) * 512 + lane * 8);
            bl[t2] = *(const f16x8*)(Bs + (rgB * 2 + 1) * 512 + lane * 8);
        }
#pragma unroll
        for (int mi = 0; mi < 4; ++mi)
#pragma unroll
            for (int ni = 0; ni < 4; ++ni) {
                acc[mi][ni] = __builtin_amdgcn_mfma_f32_16x16x32_f16(
                    ah[mi], bh[ni], acc[mi][ni], 0, 0, 0);
                acc[mi][ni] = __builtin_amdgcn_mfma_f32_16x16x32_f16(
                    ah[mi], bl[ni], acc[mi][ni], 0, 0, 0);
                acc[mi][ni] = __builtin_amdgcn_mfma_f32_16x16x32_f16(
                    al[mi], bh[ni], acc[mi][ni], 0, 0, 0);
            }
        __syncthreads();   // all reads done before next stage overwrites
    }

    // Epilogue. C/D layout (16x16): col = lane&15, row = (lane>>4)*4 + reg.
    const int g16 = lane >> 4, c16 = lane & 15;

    // Pass 1: row-side argmin (rows of bi-range over cols of bj-range).
#pragma unroll
    for (int mi = 0; mi < 4; ++mi) {
#pragma unroll
        for (int reg = 0; reg < 4; ++reg) {
            const int rloc = wr * 64 + mi * 16 + g16 * 4 + reg;
            const int i = rowBase + rloc;
            const int li = labM[rloc];
            float bestAp = __builtin_huge_valf(); int jAp = 0;
            float bestAn = __builtin_huge_valf(); int jAn = 0;
#pragma unroll
            for (int ni = 0; ni < 4; ++ni) {
                const int cloc = wc * 64 + ni * 16 + c16;
                const int jcol = colBase + cloc;
                const int lj = labN[cloc];
                const float v = acc[mi][ni][reg];
                const bool same = (li == lj);
                const float vap = (same && (i != jcol)) ? v : v + 2.0f;
                const float van = (!same) ? v : v + 2.0f;
                if (vap < bestAp) { bestAp = vap; jAp = jcol; }
                if (van < bestAn) { bestAn = van; jAn = jcol; }
            }
            unsigned long long kap =
                ((unsigned long long)orderable(bestAp) << 32) | (unsigned)jAp;
            unsigned long long kan =
                ((unsigned long long)orderable(bestAn) << 32) | (unsigned)jAn;
#pragma unroll
            for (int off = 1; off < 16; off <<= 1) {
                unsigned long long o = __shfl_xor(kap, off); kap = o < kap ? o : kap;
                o = __shfl_xor(kan, off); kan = o < kan ? o : kan;
            }
            if (c16 == 0) {
                atomicMin(&keys_ap[i], kap);
                atomicMin(&keys_an[i], kan);
            }
        }
    }

    // Pass 2 (off-diagonal only): column-side argmin via symmetry —
    // rows of bj-range get candidates with index in bi-range.
    if (bi != bj) {
#pragma unroll
        for (int ni = 0; ni < 4; ++ni) {
            const int cloc = wc * 64 + ni * 16 + c16;
            const int j = colBase + cloc;
            const int lj = labN[cloc];
            float bestAp = __builtin_huge_valf(); int iAp = 0;
            float bestAn = __builtin_huge_valf(); int iAn = 0;
#pragma unroll
            for (int mi = 0; mi < 4; ++mi)
#pragma unroll
                for (int reg = 0; reg < 4; ++reg) {
                    const int rloc = wr * 64 + mi * 16 + g16 * 4 + reg;
                    const int i = rowBase + rloc;
                    const int li = labM[rloc];
                    const float v = acc[mi][ni][reg];
                    const bool same = (li == lj);
                    const float vap = same ? v : v + 2.0f;   // i != j guaranteed off-diag
                    const float van = (!same) ? v : v + 2.0f;
                    if (vap < bestAp) { bestAp = vap; iAp = i; }
                    if (van < bestAn) { bestAn = van; iAn = i; }
                }
            unsigned long long kap =
                ((unsigned long long)orderable(bestAp) << 32) | (unsigned)iAp;
            unsigned long long kan =
                ((unsigned long long)orderable(bestAn) << 32) | (unsigned)iAn;
            // Reduce over g16 (lane bits 4,5): lanes sharing c16 share j.
#pragma unroll
            for (int off = 16; off < 64; off <<= 1) {
                unsigned long long o = __shfl_xor(kap, off); kap = o < kap ? o : kap;
                o = __shfl_xor(kan, off); kan = o < kan ? o : kan;
            }
            if (g16 == 0) {
                atomicMin(&keys_ap[j], kap);
                atomicMin(&keys_an[j], kan);
            }
        }
    }
}

__global__ void gather_rows(const float* __restrict__ A,
                            const unsigned long long* __restrict__ keys_ap,
                            const unsigned long long* __restrict__ keys_an,
                            float* __restrict__ out)
{
    const int row = blockIdx.x;
    const int t = threadIdx.x;
    const int ja = (int)(keys_ap[row] & 0xFFFFFFFFull);
    const int jn = (int)(keys_an[row] & 0xFFFFFFFFull);
    const float4* Av = (const float4*)A;
    float4* Ov = (float4*)out;
    Ov[(size_t)row * (D / 4) + t]       = Av[(size_t)ja * (D / 4) + t];
    Ov[(size_t)(N + row) * (D / 4) + t] = Av[(size_t)jn * (D / 4) + t];
}

extern "C" void kernel_launch(void* const* d_in, const int* in_sizes, int n_in,
                              void* d_out, int out_size, void* d_ws, size_t ws_size,
                              hipStream_t stream) {
    const float* A = (const float*)d_in[0];
    const int* labels = (const int*)d_in[1];  // integer inputs arrive as int32
    float* out = (float*)d_out;

    unsigned long long* keys = (unsigned long long*)d_ws;          // 64 KB
    f16* Xsw = (f16*)((char*)d_ws + 65536);                        // 16 MB hi+lo

    split_swizzle<<<N / 16, 256, 0, stream>>>(A, Xsw, keys);
    gemm_argmin_sym<<<NBLK, 256, 0, stream>>>(Xsw, labels, keys, keys + N);
    gather_rows<<<N, 256, 0, stream>>>(A, keys, keys + N, out);
}